// Round 14
// baseline (333.543 us; speedup 1.0000x reference)
//
#include <hip/hip_runtime.h>
#include <hip/hip_fp16.h>

#define NN 131072        // nodes
#define EE 2097152       // edges
#define SS 32            // channels
#define HH 16            // hidden
#define BB 4096          // graphs
#define EPS 1e-5f

#define BKT 512          // buckets (dst >> 8)
#define BNODES 256       // nodes per bucket
#define CAP 4864         // bucket capacity in words (avg 4096, +12 sigma)
#define SCAP 8192        // bucket capacity in ssrc (padded-to-16 per node)
#define TILE 8192        // edges per bsort block

typedef _Float16 f16x8 __attribute__((ext_vector_type(8)));
typedef float f32x4 __attribute__((ext_vector_type(4)));

// ---------------- bucket partition, LDS-staged, 1024 threads (16 waves/CU) ----------------
__global__ __launch_bounds__(1024) void k_bsort(const int* __restrict__ ei, int* __restrict__ gcount,
                                                int* __restrict__ words) {
    __shared__ int cnt[BKT];
    __shared__ int tstart[BKT];
    __shared__ int gshift[BKT];
    __shared__ int sc[BKT];
    __shared__ int sword[TILE];
    __shared__ int sdst[TILE];
    int t = threadIdx.x;
    if (t < BKT) cnt[t] = 0;
    __syncthreads();
    int e0 = blockIdx.x * TILE;
#pragma unroll
    for (int it = 0; it < TILE / 1024; ++it) {
        int dst = ei[EE + e0 + it * 1024 + t];
        atomicAdd(&cnt[dst >> 8], 1);
    }
    __syncthreads();
    int val = (t < BKT) ? cnt[t] : 0;
    if (t < BKT) sc[t] = val;
    __syncthreads();
    for (int d = 1; d < BKT; d <<= 1) {
        int v2 = (t >= d && t < BKT) ? sc[t - d] : 0;
        __syncthreads();
        if (t < BKT) sc[t] += v2;
        __syncthreads();
    }
    if (t < BKT) {
        int excl = sc[t] - val;
        tstart[t] = excl;
        gshift[t] = t * CAP + atomicAdd(&gcount[t], val) - excl;   // includes segment base
        cnt[t] = 0;                     // reuse as intra-tile cursor
    }
    __syncthreads();
#pragma unroll
    for (int it = 0; it < TILE / 1024; ++it) {
        int e = e0 + it * 1024 + t;
        int src = ei[e];
        int dst = ei[EE + e];
        int b = dst >> 8;
        int r = atomicAdd(&cnt[b], 1);
        int p = tstart[b] + r;
        sword[p] = src | ((dst & 255) << 17);
        sdst[p] = gshift[b] + p;        // == b*CAP + bucket_base + rank
    }
    __syncthreads();
#pragma unroll
    for (int it = 0; it < TILE / 1024; ++it) {
        int i = it * 1024 + t;
        words[sdst[i]] = sword[i];      // position-ordered: full-line bursts
    }
}

// ---------------- within-bucket sort to CSR with 16-padded node segments ----------------
__global__ __launch_bounds__(512) void k_csr(const int* __restrict__ words, const int* __restrict__ gcount,
                                             int* __restrict__ ssrc, int* __restrict__ offs,
                                             int* __restrict__ offe) {
    __shared__ int hist[BNODES];
    __shared__ int sc[BNODES];
    __shared__ int base[BNODES];
    int t = threadIdx.x;
    int b = blockIdx.x;
    if (t < BNODES) hist[t] = 0;
    __syncthreads();
    int cnt = gcount[b];
    const int* wp = words + (size_t)b * CAP;
    for (int p = t; p < cnt; p += 512) atomicAdd(&hist[wp[p] >> 17], 1);
    __syncthreads();
    int val = 0, pval = 0;
    if (t < BNODES) {
        val = hist[t];
        pval = (val + 15) & ~15;        // padded length
        sc[t] = pval;
    }
    __syncthreads();
    for (int d = 1; d < BNODES; d <<= 1) {
        int v2 = (t >= d && t < BNODES) ? sc[t - d] : 0;
        __syncthreads();
        if (t < BNODES) sc[t] += v2;
        __syncthreads();
    }
    int gbase = b * SCAP;
    if (t < BNODES) {
        base[t] = sc[t] - pval;         // exclusive scan of padded lengths
        offs[b * BNODES + t] = gbase + base[t];
        offe[b * BNODES + t] = gbase + base[t] + val;
        hist[t] = 0;                    // reuse as per-node cursor
    }
    __syncthreads();
    for (int p = t; p < cnt; p += 512) {
        int w = wp[p];
        int dl = w >> 17;
        int r = atomicAdd(&hist[dl], 1);
        ssrc[gbase + base[dl] + r] = w & 0x1FFFF;
    }
    if (t < BNODES) {                   // pad fill: disjoint range [val, pval)
        int s = gbase + base[t];
        for (int i = val; i < pval; ++i) ssrc[s + i] = NN;
    }
}

// ---------------- fused prep: weight transposes + head fold + zero-init ----------------
__global__ __launch_bounds__(256) void k_prep(const float* __restrict__ mW1, const float* __restrict__ mW2,
                                              const float* __restrict__ mW3, const float* __restrict__ vW,
                                              const float* __restrict__ vb, const float* __restrict__ aW,
                                              const float* __restrict__ ab,
                                              _Float16* __restrict__ W1T, _Float16* __restrict__ W2T,
                                              _Float16* __restrict__ W3T, _Float16* __restrict__ BqT,
                                              float* __restrict__ biasq, int* __restrict__ gcount,
                                              float* __restrict__ bns) {
    int i = blockIdx.x * 256 + threadIdx.x;     // 262144 threads
    {
        int k = i >> 8, n = i & 255;
        W1T[(size_t)n * 1024 + k] = (_Float16)mW1[i];
    }
    if (i < 65536) {
        int k = i >> 8, n = i & 255;
        W2T[n * 256 + k] = (_Float16)mW2[i];
        W3T[n * 256 + k] = (_Float16)mW3[i];
    }
    if (i < 16384) {
        int f = i >> 6, j = i & 63;
        int n = j >> 1, a = j & 1;
        float wa = aW[n * 512 + f * 2 + a];
        float wo = aW[n * 512 + f * 2 + (1 - a)];
        BqT[j * 256 + f] = (_Float16)(vW[f] + 0.5f * (wa - wo));
    }
    if (i < 64) biasq[i] = vb[0] + 0.5f * (ab[i] - ab[i ^ 1]);
    if (i < 512) gcount[i] = 0;
    if (i < 192) bns[i] = 0.f;
}

// ---------------- layer-1 pre-transform (u = x@(Wt-Wb)+b1 fp32, v = x@Wb fp16) ------------
__global__ __launch_bounds__(256) void k_pre1(const float* __restrict__ x, const float* __restrict__ W1,
                                              const float* __restrict__ b1, float* __restrict__ u,
                                              __half* __restrict__ v) {
    int t = blockIdx.x * 256 + threadIdx.x;     // N*16 threads
    int n = t >> 4, c = t & 15;
    float x0 = x[n * 2], x1 = x[n * 2 + 1];
    float w0 = W1[c], w1 = W1[16 + c], w2 = W1[32 + c], w3 = W1[48 + c];
    u[t] = b1[c] + x0 * (w0 - w2) + x1 * (w1 - w3);
    v[t] = __float2half(x0 * w2 + x1 * w3);
    if (blockIdx.x == 0 && t < 16) v[NN * 16 + t] = __float2half(-60000.0f);
}

// ---------------- fused BN+ReLU + pre-transform for layers 2/3 ----------------
__global__ __launch_bounds__(256) void k_bnpre(const float* __restrict__ y, const float* __restrict__ bns,
                                               const float* __restrict__ g, const float* __restrict__ bb,
                                               const float* __restrict__ W1, const float* __restrict__ b1,
                                               float* __restrict__ u, __half* __restrict__ v) {
    __shared__ float sh[16][33];
    __shared__ float wd[32][16];
    __shared__ float wv[32][16];
    __shared__ float scL[32], soL[32];
    int t = threadIdx.x;
    if (t < 32) {
        const float inv_n = 1.0f / (float)NN;
        float mean = bns[t] * inv_n;
        float var = bns[32 + t] * inv_n - mean * mean;
        float s = g[t] * rsqrtf(var + EPS);
        scL[t] = s;
        soL[t] = bb[t] - mean * s;
    }
    for (int i = t; i < 512; i += 256) {
        int f = i >> 4, c = i & 15;
        float wt = W1[i];
        float wb = W1[512 + i];
        wd[f][c] = wt - wb;
        wv[f][c] = wb;
    }
    __syncthreads();
    int nb = blockIdx.x * 16;
    for (int i = t; i < 512; i += 256) {
        int col = i & 31;
        sh[i >> 5][col] = fmaxf(y[nb * 32 + i] * scL[col] + soL[col], 0.f);
    }
    __syncthreads();
    int c = t & 15, nl = t >> 4;
    float uu = b1[c], vv = 0.f;
#pragma unroll
    for (int f = 0; f < 32; ++f) {
        float hv = sh[nl][f];
        uu += hv * wd[f][c];
        vv += hv * wv[f][c];
    }
    int n = nb + nl;
    u[n * 16 + c] = uu;
    v[n * 16 + c] = __float2half(vv);
    if (blockIdx.x == 0 && t < 16) v[NN * 16 + t] = __float2half(-60000.0f);
}

// ---------------- CSR gather v3: 2 lanes/edge, float4 row-halves, shfl reduce ----------------
// R13 theory: previous shape issued 32M VMEM ops/layer (8x redundant ssrc + 4B v loads).
// Now lane s (0..7) of a node handles edge slot s>>1, row half s&1: 16B row loads, 2x idx
// redundancy => ~9M loads/layer. Edge-slot partials combine via shfl_xor(2),(4).
__global__ __launch_bounds__(256) void k_gather(const float* __restrict__ u, const __half* __restrict__ v,
                                                const int* __restrict__ ssrc, const int* __restrict__ offs,
                                                const int* __restrict__ offe,
                                                const float* __restrict__ W2, const float* __restrict__ b2,
                                                float* __restrict__ y) {
    __shared__ float sw2[512];          // [k][32]
    __shared__ float sagg[32 * 18];
    __shared__ float cntL[32];
    int t = threadIdx.x;
    float w2a = W2[t], w2b = W2[t + 256];         // stage in regs; LDS write after gather
    float b2r0 = b2[(t & 7) * 4], b2r1 = b2[(t & 7) * 4 + 1];
    float b2r2 = b2[(t & 7) * 4 + 2], b2r3 = b2[(t & 7) * 4 + 3];
    int nl = t >> 3, s = t & 7;
    int e2 = s >> 1;                    // edge slot 0..3
    int h = s & 1;                      // row half (8 channels)
    int n = blockIdx.x * 32 + nl;
    int s0 = offs[n], e0 = offe[n];
    int pe = s0 + ((e0 - s0 + 15) & ~15);
    float ur[8];
    *(float4*)&ur[0] = *(const float4*)(u + (size_t)n * 16 + h * 8);
    *(float4*)&ur[4] = *(const float4*)(u + (size_t)n * 16 + h * 8 + 4);
    float acc[8] = {};
    for (int p = s0; p < pe; p += 16) {
        int b0 = p + e2;
        int i0 = ssrc[b0], i1 = ssrc[b0 + 4], i2 = ssrc[b0 + 8], i3 = ssrc[b0 + 12];
        float4 r0 = ((const float4*)(v + (size_t)i0 * 16))[h];
        float4 r1 = ((const float4*)(v + (size_t)i1 * 16))[h];
        float4 r2 = ((const float4*)(v + (size_t)i2 * 16))[h];
        float4 r3 = ((const float4*)(v + (size_t)i3 * 16))[h];
        const float4* rs[4] = {&r0, &r1, &r2, &r3};
#pragma unroll
        for (int e = 0; e < 4; ++e) {
            const __half2* hp = (const __half2*)rs[e];
#pragma unroll
            for (int k = 0; k < 4; ++k) {
                float2 f = __half22float2(hp[k]);
                acc[2 * k]     += fmaxf(ur[2 * k] + f.x, 0.f);
                acc[2 * k + 1] += fmaxf(ur[2 * k + 1] + f.y, 0.f);
            }
        }
    }
    // combine the 4 edge-slot copies (lanes differing in s bits 1-2)
#pragma unroll
    for (int j = 0; j < 8; ++j) {
        acc[j] += __shfl_xor(acc[j], 2);
        acc[j] += __shfl_xor(acc[j], 4);
    }
    if (e2 == 0) {                      // s==0 (ch 0-7) and s==1 (ch 8-15)
#pragma unroll
        for (int j = 0; j < 8; ++j) sagg[nl * 18 + h * 8 + j] = acc[j];
    }
    if (s == 0) cntL[nl] = (float)(e0 - s0);
    sw2[t] = w2a;
    sw2[t + 256] = w2b;
    __syncthreads();
    int node = t >> 3, oc = (t & 7) * 4;
    float cw = cntL[node];
    float o0 = b2r0 * cw, o1 = b2r1 * cw, o2 = b2r2 * cw, o3 = b2r3 * cw;
#pragma unroll
    for (int k = 0; k < 16; ++k) {
        float a = sagg[node * 18 + k];
        o0 += a * sw2[k * 32 + oc];
        o1 += a * sw2[k * 32 + oc + 1];
        o2 += a * sw2[k * 32 + oc + 2];
        o3 += a * sw2[k * 32 + oc + 3];
    }
    *(float4*)(y + (size_t)(blockIdx.x * 32 + node) * 32 + oc) = make_float4(o0, o1, o2, o3);
}

// ---------------- BN stats straight from y: 256 blocks x 512 rows ----------------
__global__ __launch_bounds__(256) void k_bnstat2(const float* __restrict__ y, float* __restrict__ bns) {
    __shared__ float ssm[8][33];
    __shared__ float ssq[8][33];
    int t = threadIdx.x;
    int c = t & 31, g = t >> 5;
    size_t r0 = (size_t)blockIdx.x * 512;
    float sm = 0.f, sq = 0.f;
    for (int i = 0; i < 64; ++i) {
        float val = y[(r0 + g + (size_t)i * 8) * 32 + c];
        sm += val;
        sq += val * val;
    }
    ssm[g][c] = sm;
    ssq[g][c] = sq;
    __syncthreads();
    if (t < 32) {
        float a = 0.f, bq = 0.f;
#pragma unroll
        for (int gg = 0; gg < 8; ++gg) { a += ssm[gg][t]; bq += ssq[gg][t]; }
        atomicAdd(&bns[t], a);
        atomicAdd(&bns[32 + t], bq);
    }
}

// ---------------- layer-3 BN+ReLU -> fp16 GEMM input only ----------------
__global__ __launch_bounds__(256) void k_bnrelu16(const float* __restrict__ y, const float* __restrict__ bns,
                                                  const float* __restrict__ g, const float* __restrict__ bb,
                                                  _Float16* __restrict__ h16) {
    int t = blockIdx.x * 256 + threadIdx.x;
    int j = t & 31;
    const float inv_n = 1.0f / (float)NN;
    float mean = bns[j] * inv_n;
    float var = bns[32 + j] * inv_n - mean * mean;
    float sc = g[j] * rsqrtf(var + EPS);
    float sh = bb[j] - mean * sc;
    h16[t] = (_Float16)fmaxf(y[t] * sc + sh, 0.f);
}

// ---------------- MFMA fp16 GEMM: C = [relu](A[M,K] @ BT[N,K]^T + bias) ----------------
__global__ __launch_bounds__(256) void k_mgemm(const _Float16* __restrict__ A, const _Float16* __restrict__ BT,
                                               const float* __restrict__ bias, float* __restrict__ Cf,
                                               _Float16* __restrict__ Ch, int M, int N, int K,
                                               int relu, int out16) {
    int tid = threadIdx.x;
    int w = tid >> 6, l = tid & 63, q = l >> 4, r = l & 15;
    int rowBase = blockIdx.x * 64;
    int col = blockIdx.y * 64 + w * 16 + r;
    const _Float16* ap = A + (size_t)(rowBase + r) * K + q * 8;
    const _Float16* bp = BT + (size_t)col * K + q * 8;
    f32x4 z = {0.f, 0.f, 0.f, 0.f};
    f32x4 acc[4] = {z, z, z, z};
    for (int k0 = 0; k0 < K; k0 += 32) {
        f16x8 bf = *(const f16x8*)(bp + k0);
        f16x8 a0 = *(const f16x8*)(ap + k0);
        f16x8 a1 = *(const f16x8*)(ap + k0 + (size_t)16 * K);
        f16x8 a2 = *(const f16x8*)(ap + k0 + (size_t)32 * K);
        f16x8 a3 = *(const f16x8*)(ap + k0 + (size_t)48 * K);
        acc[0] = __builtin_amdgcn_mfma_f32_16x16x32_f16(a0, bf, acc[0], 0, 0, 0);
        acc[1] = __builtin_amdgcn_mfma_f32_16x16x32_f16(a1, bf, acc[1], 0, 0, 0);
        acc[2] = __builtin_amdgcn_mfma_f32_16x16x32_f16(a2, bf, acc[2], 0, 0, 0);
        acc[3] = __builtin_amdgcn_mfma_f32_16x16x32_f16(a3, bf, acc[3], 0, 0, 0);
    }
    float bv = bias[col];
#pragma unroll
    for (int rt = 0; rt < 4; ++rt) {
#pragma unroll
        for (int i = 0; i < 4; ++i) {
            int row = rowBase + rt * 16 + q * 4 + i;
            float val = acc[rt][i] + bv;
            if (relu) val = fmaxf(val, 0.f);
            if (out16) Ch[(size_t)row * N + col] = (_Float16)val;
            else       Cf[(size_t)row * N + col] = val;
        }
    }
}

extern "C" void kernel_launch(void* const* d_in, const int* in_sizes, int n_in,
                              void* d_out, int out_size, void* d_ws, size_t ws_size,
                              hipStream_t stream) {
    const float* x    = (const float*)d_in[0];
    const int*   ei   = (const int*)d_in[1];
    const float* c1W1 = (const float*)d_in[2];
    const float* c1b1 = (const float*)d_in[3];
    const float* c1W2 = (const float*)d_in[4];
    const float* c1b2 = (const float*)d_in[5];
    const float* c2W1 = (const float*)d_in[6];
    const float* c2b1 = (const float*)d_in[7];
    const float* c2W2 = (const float*)d_in[8];
    const float* c2b2 = (const float*)d_in[9];
    const float* c3W1 = (const float*)d_in[10];
    const float* c3b1 = (const float*)d_in[11];
    const float* c3W2 = (const float*)d_in[12];
    const float* c3b2 = (const float*)d_in[13];
    const float* bn_g = (const float*)d_in[14];
    const float* bn_b = (const float*)d_in[15];
    const float* mW1  = (const float*)d_in[16];
    const float* mb1  = (const float*)d_in[17];
    const float* mW2  = (const float*)d_in[18];
    const float* mb2  = (const float*)d_in[19];
    const float* mW3  = (const float*)d_in[20];
    const float* mb3  = (const float*)d_in[21];
    const float* vW   = (const float*)d_in[22];
    const float* vb   = (const float*)d_in[23];
    const float* aW   = (const float*)d_in[24];
    const float* ab   = (const float*)d_in[25];
    float* out = (float*)d_out;

    char* p = (char*)d_ws;
    auto take = [&](size_t bytes) {
        char* r = p;
        p += (bytes + 255) & ~(size_t)255;
        return r;
    };
    int*       gcount = (int*)take((size_t)BKT * 4);
    int*       words  = (int*)take((size_t)BKT * CAP * 4);       // ~10 MB bucketed edges
    int*       ssrc   = (int*)take((size_t)BKT * SCAP * 4);      // 16 MB padded CSR srcs
    int*       offs   = (int*)take((size_t)NN * 4);
    int*       offe   = (int*)take((size_t)NN * 4);
    float*     u      = (float*)take((size_t)NN * HH * 4);
    __half*    v      = (__half*)take((size_t)(NN + 1) * HH * 2);
    float*     y      = (float*)take((size_t)NN * SS * 4);
    _Float16*  h16    = (_Float16*)take((size_t)NN * SS * 2);
    float*     bns    = (float*)take(3 * 64 * 4);
    _Float16*  W1T    = (_Float16*)take((size_t)256 * 1024 * 2);
    _Float16*  W2T    = (_Float16*)take((size_t)256 * 256 * 2);
    _Float16*  W3T    = (_Float16*)take((size_t)256 * 256 * 2);
    _Float16*  BqT    = (_Float16*)take((size_t)64 * 256 * 2);
    float*     biasq  = (float*)take(64 * 4);
    _Float16*  Xa     = (_Float16*)take((size_t)BB * 256 * 2);
    _Float16*  Xb     = (_Float16*)take((size_t)BB * 256 * 2);

    // fused prep (weights transpose + head fold + gcount/bns zero-init)
    k_prep<<<1024, 256, 0, stream>>>(mW1, mW2, mW3, vW, vb, aW, ab,
                                     W1T, W2T, W3T, BqT, biasq, gcount, bns);

    // CSR build: LDS-staged bucket partition (1024 thr), then padded within-bucket sort
    k_bsort<<<EE / TILE, 1024, 0, stream>>>(ei, gcount, words);
    k_csr<<<BKT, 512, 0, stream>>>(words, gcount, ssrc, offs, offe);

    // layer 1
    k_pre1<<<NN * 16 / 256, 256, 0, stream>>>(x, c1W1, c1b1, u, v);
    k_gather<<<NN / 32, 256, 0, stream>>>(u, v, ssrc, offs, offe, c1W2, c1b2, y);
    k_bnstat2<<<256, 256, 0, stream>>>(y, bns);
    // layer 2 (fused BN+ReLU+pre)
    k_bnpre<<<NN / 16, 256, 0, stream>>>(y, bns, bn_g, bn_b, c2W1, c2b1, u, v);
    k_gather<<<NN / 32, 256, 0, stream>>>(u, v, ssrc, offs, offe, c2W2, c2b2, y);
    k_bnstat2<<<256, 256, 0, stream>>>(y, bns + 64);
    // layer 3 (fused BN+ReLU+pre)
    k_bnpre<<<NN / 16, 256, 0, stream>>>(y, bns + 64, bn_g + 32, bn_b + 32, c3W1, c3b1, u, v);
    k_gather<<<NN / 32, 256, 0, stream>>>(u, v, ssrc, offs, offe, c3W2, c3b2, y);
    k_bnstat2<<<256, 256, 0, stream>>>(y, bns + 128);
    k_bnrelu16<<<NN * 32 / 256, 256, 0, stream>>>(y, bns + 128, bn_g + 64, bn_b + 64, h16);

    // dense head MLP on matrix cores (fp16 in, fp32 accumulate)
    k_mgemm<<<dim3(BB / 64, 4), 256, 0, stream>>>(h16, W1T, mb1, nullptr, Xa, BB, 256, 1024, 1, 1);
    k_mgemm<<<dim3(BB / 64, 4), 256, 0, stream>>>(Xa, W2T, mb2, nullptr, Xb, BB, 256, 256, 1, 1);
    k_mgemm<<<dim3(BB / 64, 4), 256, 0, stream>>>(Xb, W3T, mb3, nullptr, Xa, BB, 256, 256, 1, 1);
    // dueling heads folded into one GEMM: out = X @ BqT^T + biasq
    k_mgemm<<<dim3(BB / 64, 1), 256, 0, stream>>>(Xa, BqT, biasq, out, nullptr, BB, 64, 256, 0, 0);
}